// Round 18
// baseline (120.742 us; speedup 1.0000x reference)
//
#include <hip/hip_runtime.h>

#define N_ROWS 400000
#define KIN 128
#define KOUT 64
#define RPW 4                       // rows per wave per batch
#define WPB 2                       // waves per block
#define NB  2                       // batches per wave (2-deep pipeline)
#define G_BLOCKS (N_ROWS / (WPB * RPW * NB))   // 25000 blocks (short-lived)
#define TOT_WAVES (G_BLOCKS * WPB)             // 50000 waves
#define TOT_WB (N_ROWS / RPW)                  // 100000 wave-batches

typedef unsigned int uint32;
typedef unsigned int v2u __attribute__((ext_vector_type(2)));

// R18: 2-deep pipelined, NON-persistent (the R11/R15 persistent failures came
// from long-lived-block residency/drain, not from prefetch itself). Each wave
// does exactly 2 batches; batch 1's loads issue before batch 0's sort, so
// half the cold-load stalls are hidden while blocks stay short and the grid
// stays at 25000 for even distribution. NT stores kept from R17.
//
// Key/network (R14): 32-bit key (d*2^24)<<7|col (|0x80000000 if invalid),
// B stored complemented; twin 64-sorts (same masks) -> min(keyA,~keyB') ->
// 6-stage ascending merge -> lane=rank. CE = exchange + v_med3_u32 with
// VGPR mask. Zero-DS network. DS = nidx stash only (gather of batch b
// precedes stash of b+1 in program order; DS is in-order per wave -> safe).

template <int CTRL>
__device__ __forceinline__ uint32 dpp32(uint32 k) {
    return (uint32)__builtin_amdgcn_update_dpp(0, (int)k, CTRL, 0xF, 0xF, true);
}
__device__ __forceinline__ uint32 x4swap(uint32 k) {
    uint32 o = (uint32)__builtin_amdgcn_update_dpp((int)k, (int)k, 0x104, 0xF, 0x5, true);
    o = (uint32)__builtin_amdgcn_update_dpp((int)o, (int)k, 0x114, 0xF, 0xA, true);
    return o;
}
__device__ __forceinline__ void pl32pair(uint32 k, uint32& A, uint32& B) {
    const v2u r = __builtin_amdgcn_permlane32_swap(k, k, false, false);
    A = r[0]; B = r[1];
}
#if __has_builtin(__builtin_amdgcn_permlane16_swap)
__device__ __forceinline__ void pl16pair(uint32 k, uint32& A, uint32& B) {
    const v2u r = __builtin_amdgcn_permlane16_swap(k, k, false, false);
    A = r[0]; B = r[1];
}
#else
__device__ __forceinline__ void pl16pair(uint32 k, uint32& A, uint32& B) {
    A = k; B = (uint32)__builtin_amdgcn_ds_swizzle((int)k, 0x401F);
}
#endif
__device__ __forceinline__ uint32 umin32(uint32 a, uint32 b) { return a < b ? a : b; }
__device__ __forceinline__ uint32 med3(uint32 a, uint32 b, uint32 m) {
    uint32 d;
    asm("v_med3_u32 %0, %1, %2, %3" : "=v"(d) : "v"(a), "v"(b), "v"(m));
    return d;
}

#define T_DPP(CTRL, M) { _Pragma("unroll") \
    for (int r_ = 0; r_ < RPW; ++r_) { \
        keyA[r_] = med3(keyA[r_], dpp32<CTRL>(keyA[r_]), M); \
        keyB[r_] = med3(keyB[r_], dpp32<CTRL>(keyB[r_]), M); } }
#define T_X4(M) { _Pragma("unroll") \
    for (int r_ = 0; r_ < RPW; ++r_) { \
        keyA[r_] = med3(keyA[r_], x4swap(keyA[r_]), M); \
        keyB[r_] = med3(keyB[r_], x4swap(keyB[r_]), M); } }
#define T_PL16(M) { _Pragma("unroll") \
    for (int r_ = 0; r_ < RPW; ++r_) { \
        uint32 A0, B0, A1, B1; \
        pl16pair(keyA[r_], A0, B0); pl16pair(keyB[r_], A1, B1); \
        keyA[r_] = med3(A0, B0, M); keyB[r_] = med3(A1, B1, M); } }
#define T_PL32(M) { _Pragma("unroll") \
    for (int r_ = 0; r_ < RPW; ++r_) { \
        uint32 A0, B0, A1, B1; \
        pl32pair(keyA[r_], A0, B0); pl32pair(keyB[r_], A1, B1); \
        keyA[r_] = med3(A0, B0, M); keyB[r_] = med3(A1, B1, M); } }
#define M_DPP(CTRL, M) { _Pragma("unroll") \
    for (int r_ = 0; r_ < RPW; ++r_) { \
        keyA[r_] = med3(keyA[r_], dpp32<CTRL>(keyA[r_]), M); } }
#define M_X4(M) { _Pragma("unroll") \
    for (int r_ = 0; r_ < RPW; ++r_) { \
        keyA[r_] = med3(keyA[r_], x4swap(keyA[r_]), M); } }
#define M_PL16(M) { _Pragma("unroll") \
    for (int r_ = 0; r_ < RPW; ++r_) { \
        uint32 A, B; pl16pair(keyA[r_], A, B); keyA[r_] = med3(A, B, M); } }
#define M_PL32(M) { _Pragma("unroll") \
    for (int r_ = 0; r_ < RPW; ++r_) { \
        uint32 A, B; pl32pair(keyA[r_], A, B); keyA[r_] = med3(A, B, M); } }

#define QP_X1 0xB1   // quad_perm [1,0,3,2] : xor1
#define QP_X2 0x4E   // quad_perm [2,3,0,1] : xor2
#define ROR8  0x128  // row_ror:8           : xor8

__global__ __launch_bounds__(128) void SortAndSelectNeighbours_kernel(
    const float* __restrict__ distances,
    const int*   __restrict__ nidx,
    float*       __restrict__ out)
{
    __shared__ int s_nidx[WPB][RPW][KIN];   // 4 KB/block, per-wave private

    const int lane = threadIdx.x & 63;
    const int wid  = threadIdx.x >> 6;
    const int c0   = 2 * lane;
    const uint32 waveg = (uint32)blockIdx.x * WPB + (uint32)wid;

    // per-lane direction masks as VGPR bit-patterns (0 / ~0)
    const uint32 lm = (uint32)lane;
    const uint32 m0 = (uint32)-(int)(lm & 1u);
    const uint32 m1 = (uint32)-(int)((lm >> 1) & 1u);
    const uint32 m2 = (uint32)-(int)((lm >> 2) & 1u);
    const uint32 m3 = (uint32)-(int)((lm >> 3) & 1u);
    const uint32 m4 = (uint32)-(int)((lm >> 4) & 1u);
    const uint32 m5 = (uint32)-(int)((lm >> 5) & 1u);
    const uint32 g01 = m0 ^ m1;
    const uint32 g12 = m1 ^ m2, g02 = m0 ^ m2;
    const uint32 g23 = m2 ^ m3, g13 = m1 ^ m3, g03 = m0 ^ m3;
    const uint32 g34 = m3 ^ m4, g24 = m2 ^ m4, g14 = m1 ^ m4, g04 = m0 ^ m4;
    const uint32 g45 = m4 ^ m5, g35 = m3 ^ m5, g25 = m2 ^ m5, g15 = m1 ^ m5,
                 g05 = m0 ^ m5;

    // ---- load batch 0 ----
    uint32 wb = waveg;
    float2 dv[RPW];
    int2   nv[RPW];
    #pragma unroll
    for (int r = 0; r < RPW; ++r) {
        const uint32 off = (wb * RPW + (uint32)r) * KIN + (uint32)c0;
        dv[r] = *reinterpret_cast<const float2*>(distances + off);
        nv[r] = *reinterpret_cast<const int2*>(nidx + off);
    }

    #pragma unroll 1
    for (int it = 0; it < NB; ++it) {
        // ---- stash payload + build keys (consumes dv/nv) ----
        uint32 keyA[RPW], keyB[RPW];
        #pragma unroll
        for (int r = 0; r < RPW; ++r) {
            *reinterpret_cast<int2*>(&s_nidx[wid][r][c0]) = nv[r];
            const uint32 k0 = (uint32)(dv[r].x * 16777216.0f);  // exact
            const uint32 k1 = (uint32)(dv[r].y * 16777216.0f);
            keyA[r] =  (((k0 << 7) | (uint32)c0)       | ((uint32)nv[r].x & 0x80000000u));
            keyB[r] = ~(((k1 << 7) | (uint32)(c0 + 1)) | ((uint32)nv[r].y & 0x80000000u));
        }

        // ---- prefetch batch 1 into the dead dv/nv (hidden under sort 0) ----
        if (it == 0) {
            const uint32 wb2 = wb + (uint32)TOT_WAVES;
            #pragma unroll
            for (int r = 0; r < RPW; ++r) {
                const uint32 off = (wb2 * RPW + (uint32)r) * KIN + (uint32)c0;
                dv[r] = *reinterpret_cast<const float2*>(distances + off);
                nv[r] = *reinterpret_cast<const int2*>(nidx + off);
            }
        }

        // ---- twin bitonic 64-sorts (A asc; B asc in complement space) ----
        T_DPP(QP_X1, g01);                                            // k=2
        T_DPP(QP_X2, g12); T_DPP(QP_X1, g02);                         // k=4
        T_X4(g23); T_DPP(QP_X2, g13); T_DPP(QP_X1, g03);              // k=8
        T_DPP(ROR8, g34); T_X4(g24); T_DPP(QP_X2, g14);               // k=16
        T_DPP(QP_X1, g04);
        T_PL16(g45); T_DPP(ROR8, g35); T_X4(g25); T_DPP(QP_X2, g15);  // k=32
        T_DPP(QP_X1, g05);
        T_PL32(m5); T_PL16(m4); T_DPP(ROR8, m3); T_X4(m2);            // k=64
        T_DPP(QP_X2, m1); T_DPP(QP_X1, m0);

        // ---- min-merge -> ascending merge of 64 -> lane = rank ----
        #pragma unroll
        for (int r = 0; r < RPW; ++r)
            keyA[r] = umin32(keyA[r], ~keyB[r]);
        M_PL32(m5); M_PL16(m4); M_DPP(ROR8, m3); M_X4(m2);
        M_DPP(QP_X2, m1); M_DPP(QP_X1, m0);

        // ---- epilogue (NT stores; LDS gather precedes next stash) ----
        #pragma unroll
        for (int r = 0; r < RPW; ++r) {
            const bool bey = keyA[r] > 0x4000007Fu;   // d > 0.5 strictly
            const float d = (float)(keyA[r] >> 7) * 5.9604644775390625e-8f;
            const int col = (int)(keyA[r] & 127u);
            const int n   = s_nidx[wid][r][col];

            const uint32 od = (wb * RPW + (uint32)r) * KOUT + (uint32)lane;
            __builtin_nontemporal_store(bey ? 0.0f : d, &out[od]);
            __builtin_nontemporal_store(bey ? -1.0f : (float)n,
                                        &out[(uint32)(N_ROWS * KOUT) + od]);
        }

        wb += (uint32)TOT_WAVES;
    }
}

extern "C" void kernel_launch(void* const* d_in, const int* in_sizes, int n_in,
                              void* d_out, int out_size, void* d_ws, size_t ws_size,
                              hipStream_t stream) {
    const float* distances = (const float*)d_in[0];
    const int*   nidx      = (const int*)d_in[1];
    float*       out       = (float*)d_out;

    dim3 grid(G_BLOCKS);   // 25000 short-lived blocks, 2 batches per wave
    dim3 block(128);
    hipLaunchKernelGGL(SortAndSelectNeighbours_kernel, grid, block, 0, stream,
                       distances, nidx, out);
}